// Round 13
// baseline (472.864 us; speedup 1.0000x reference)
//
#include <hip/hip_runtime.h>
#include <hip/hip_bf16.h>

#define NTOT   65536
#define NEDGE  1048576
#define HEADS  5
#define K1     32
#define K2     8
#define MEMH   100
#define EPSF   1e-8f

// ---- workspace layout (bytes) ----
#define OFF_DEG     0x0000000   // deg[65536]; doubles as bh2[256*256] before k_fine
#define OFF_BH2     0x0000000
#define OFF_WT1     0x0040000
#define OFF_WT2     0x0050000   // ends 0x70000
#define OFF_OFFS    0x0080000
#define OFF_BNSUM   0x00C0000   // f32[128]
#define OFF_BNSQ    0x00C0400   // f32[128]
#define OFF_SCALE   0x00C0800
#define OFF_SHIFT   0x00C0A00
#define OFF_KSQ0    0x00C0C00
#define OFF_KSQ1    0x00C0E80
#define OFF_KL      0x00C0F40
#define OFF_FLAG    0x00C0F60
#define OFF_W       0x00C1000   // f32 weights
#define OFF_K0B     0x0128000   // keys0 bf16 (40KB)
#define OFF_CN      0x0134000   // cn[256*32] f32
#define OFF_EBASE   0x013C400
#define OFF_BCUR    0x013C800
#define OFF_CSR     0x0140000   // ushort csr: 2MB
#define OFF_A       0x0540000   // 32MB: agH64(8)+agL64(8) -> agH128(16)+agL128(16)
#define OFF_AH128   0x0540000
#define OFF_AL128   0x1540000
#define OFF_AH64    0x0540000
#define OFF_AL64    0x0D40000
#define OFF_B       0x2540000   // 32MB: ebuf(4MB, dead after k_fine) -> qvH(16)+qvL(16)
#define OFF_EBUF    0x2540000
#define OFF_QH      0x2540000
#define OFF_QL      0x3540000
#define OFF_C       0x4540000   // 16MB: xcH(8)+xcL(8) -> Cg(8)+V(4)+mq1+mq2
#define OFF_XH      0x4540000
#define OFF_XL      0x4D40000
#define OFF_CG      0x4540000
#define OFF_V       0x4D40000
#define OFF_MQ1     0x5140000
#define OFF_MQ2     0x5460000
// peak ws: 0x5540000 (proven footprint)

// ---- canonical weight offsets (floats) ----
#define W_WREL0  0
#define W_BREL0  8192
#define W_WROOT0 8320
#define W_WREL1  16512
#define W_BREL1  32896
#define W_WROOT1 33024
#define W_GAMMA  49408
#define W_BETA   49536
#define W_KEYS0  49664
#define W_CONVW0 70144
#define W_LINW0  70149
#define W_LINB0  82949
#define W_KEYS1  83049
#define W_CONVW1 87049
#define W_LINW1  87054
#define W_LINB1  97054
#define W_MLPW1  97154
#define W_MLPB1  102154
#define W_MLPW2  102204
#define W_MLPB2  102804
#define W_TOTAL  102816

typedef __attribute__((ext_vector_type(8))) short  bf16x8;
typedef __attribute__((ext_vector_type(4))) float  f32x4;

__device__ __forceinline__ float bf2f(unsigned short u){
  union { unsigned int i; float f; } v; v.i = ((unsigned int)u) << 16; return v.f;
}
__device__ __forceinline__ unsigned short f2bf(float f){
  union { float f; unsigned int i; } v; v.f = f;
  unsigned int r = (v.i + 0x7FFFu + ((v.i >> 16) & 1u)) >> 16;   // RNE
  return (unsigned short)r;
}

__device__ const int g_seg[21] = {0,8192,8320,16512,32896,33024,49408,49536,49664,
                                  70144,70149,82949,83049,87049,87054,97054,97154,
                                  102154,102204,102804,102816};
struct WPtrs { const void* p[20]; };

__device__ __forceinline__ float rdw(const void* p, int j, int flag){
  return flag ? bf2f(((const unsigned short*)p)[j]) : ((const float*)p)[j];
}

// ---------------- k_pre: detect + init + bin1 ----------------
__global__ __launch_bounds__(256) void k_pre(const unsigned short* __restrict__ xr,
                                             const int* __restrict__ dst,
                                             int* flag, float* bnsum, float* bnsq,
                                             float* kl, float* cn, int* bh2){
  __shared__ int hist[256];
  const int b = blockIdx.x, t = threadIdx.x;
  hist[t] = 0; __syncthreads();
  const int e0 = b*4096 + t;
  #pragma unroll 4
  for(int j=0;j<16;j++) atomicAdd(&hist[dst[e0 + j*256] >> 8], 1);
  __syncthreads();
  bh2[b*256 + t] = hist[t];
  if(b == 0){
    if(t < 64){
      unsigned short u = xr[2*t];
      int e = (u >> 7) & 0xFF;
      bool plaus = (u != 0) && (e >= 115) && (e <= 135);
      unsigned long long m = __ballot(plaus);
      if(t == 0) flag[0] = (__popcll(m) >= 48) ? 1 : 0;
    }
    if(t < 128){ bnsum[t]=0.f; bnsq[t]=0.f; }
    if(t < 2) kl[t]=0.f;
  }
  if(b < 32) cn[b*256 + t] = 0.f;
}

__global__ __launch_bounds__(256) void k_bscan(const int* __restrict__ bh2,
                                               int* ebase, int* bcur){
  __shared__ int ts[256];
  const int t = threadIdx.x;
  int s = 0;
  for(int b=0;b<256;b++) s += bh2[b*256 + t];
  ts[t] = s; __syncthreads();
  for(int off=1; off<256; off<<=1){
    int v = (t>=off) ? ts[t-off] : 0;
    __syncthreads(); ts[t] += v; __syncthreads();
  }
  int ex = (t==0) ? 0 : ts[t-1];
  ebase[t] = ex; bcur[t] = ex;
}

__global__ __launch_bounds__(256) void k_bin2(const int* __restrict__ src, const int* __restrict__ dst,
                                              int* bcur, unsigned int* __restrict__ ebuf){
  __shared__ int hist[256], lofs[256], lcur[256], gbase[256];
  __shared__ unsigned int sbuf[4096];
  const int t = threadIdx.x;
  hist[t] = 0; __syncthreads();
  const int e0 = blockIdx.x*4096;
  unsigned int pair[16]; int bk[16];
  #pragma unroll 4
  for(int j=0;j<16;j++){
    int e = e0 + t + j*256;
    int s = src[e], d = dst[e];
    pair[j] = (((unsigned)d)<<16) | (unsigned)s;
    bk[j] = d>>8;
    atomicAdd(&hist[bk[j]], 1);
  }
  __syncthreads();
  lcur[t] = hist[t]; __syncthreads();
  for(int off=1; off<256; off<<=1){
    int v = (t>=off) ? lcur[t-off] : 0;
    __syncthreads(); lcur[t] += v; __syncthreads();
  }
  lofs[t] = (t==0) ? 0 : lcur[t-1];
  __syncthreads();
  lcur[t] = lofs[t];
  if(hist[t]) gbase[t] = atomicAdd(&bcur[t], hist[t]);
  __syncthreads();
  #pragma unroll 4
  for(int j=0;j<16;j++){
    int p = atomicAdd(&lcur[bk[j]], 1);
    sbuf[p] = pair[j];
  }
  __syncthreads();
  const int n = hist[t], lo = lofs[t], go = gbase[t];
  for(int i=0;i<n;i++) ebuf[go + i] = sbuf[lo + i];
}

__global__ __launch_bounds__(256) void k_fine(const unsigned int* __restrict__ ebuf,
                                              const int* __restrict__ ebase,
                                              unsigned short* __restrict__ csr,
                                              int* __restrict__ deg, int* __restrict__ offs){
  __shared__ int ldeg[256], lofs[256], lcur[256];
  __shared__ unsigned int led[8192];
  __shared__ unsigned short lcsr[8192];
  const int b = blockIdx.x, t = threadIdx.x;
  const int base = ebase[b];
  const int n = ((b==255) ? NEDGE : ebase[b+1]) - base;
  ldeg[t] = 0; __syncthreads();
  for(int i=t; i<n; i+=256){
    unsigned int p = ebuf[base+i];
    led[i] = p;
    atomicAdd(&ldeg[(p>>16)&255], 1);
  }
  __syncthreads();
  lcur[t] = ldeg[t]; __syncthreads();
  for(int off=1; off<256; off<<=1){
    int v = (t>=off) ? lcur[t-off] : 0;
    __syncthreads(); lcur[t] += v; __syncthreads();
  }
  lofs[t] = (t==0) ? 0 : lcur[t-1];
  __syncthreads();
  lcur[t] = lofs[t];
  __syncthreads();
  for(int i=t; i<n; i+=256){
    unsigned int p = led[i];
    int d = (p>>16)&255;
    int pos = atomicAdd(&lcur[d], 1);
    lcsr[pos] = (unsigned short)(p & 0xFFFF);
  }
  __syncthreads();
  for(int i=t; i<n; i+=256) csr[base+i] = lcsr[i];
  deg[b*256 + t]  = ldeg[t];
  offs[b*256 + t] = base + lofs[t];
}

// ---------------- conversions ----------------
__global__ __launch_bounds__(256) void k_cvtx(const void* __restrict__ xin,
                                              const int* __restrict__ flag,
                                              unsigned short* __restrict__ xH,
                                              unsigned short* __restrict__ xL){
  int i = blockIdx.x*256 + threadIdx.x;          // NTOT*64
  float v = rdw(xin, i, flag[0]);
  unsigned short h = f2bf(v);
  xH[i] = h;
  xL[i] = f2bf(v - bf2f(h));
}

__global__ __launch_bounds__(256) void k_cvtw(WPtrs wp, const int* __restrict__ flag,
                                              float* __restrict__ wout,
                                              unsigned short* __restrict__ k0b,
                                              unsigned short* __restrict__ wt1,
                                              unsigned short* __restrict__ wt2){
  const int fl = flag[0];
  if(blockIdx.x < 402){
    int i = blockIdx.x*256 + threadIdx.x;
    if(i >= W_TOTAL) return;
    int s = 0;
    #pragma unroll
    for(int k=0;k<20;k++) if(i >= g_seg[k+1]) s = k+1;
    wout[i] = rdw(wp.p[s], i - g_seg[s], fl);
  } else {
    int i = (blockIdx.x-402)*256 + threadIdx.x;
    if(i < HEADS*K1*128) k0b[i] = f2bf(rdw(wp.p[8], i, fl));
    if(i < 128*64){
      int col = i>>6, k = i&63;
      float wr = rdw(wp.p[0], k*128 + col, fl);
      float wo = rdw(wp.p[2], k*128 + col, fl);
      unsigned short rh = f2bf(wr), oh = f2bf(wo);
      wt1[i]         = rh;
      wt1[ 8192 + i] = f2bf(wr - bf2f(rh));
      wt1[16384 + i] = oh;
      wt1[24576 + i] = f2bf(wo - bf2f(oh));
    }
    if(i < 128*128){
      int col = i>>7, k = i&127;
      float wr = rdw(wp.p[3], k*128 + col, fl);
      float wo = rdw(wp.p[5], k*128 + col, fl);
      unsigned short rh = f2bf(wr), oh = f2bf(wo);
      wt2[i]         = rh;
      wt2[16384 + i] = f2bf(wr - bf2f(rh));
      wt2[32768 + i] = oh;
      wt2[49152 + i] = f2bf(wo - bf2f(oh));
    }
  }
}

// ---------------- graph aggregation (16B bf16x8 gathers) ----------------
__global__ __launch_bounds__(256) void k_aggr64(const unsigned short* __restrict__ xH,
                                                const int* __restrict__ offs, const int* __restrict__ deg,
                                                const unsigned short* __restrict__ csr,
                                                unsigned short* __restrict__ aH,
                                                unsigned short* __restrict__ aL){
  const int wid  = (blockIdx.x*256 + threadIdx.x) >> 6;
  const int lane = threadIdx.x & 63;
  const int sub = lane >> 3, fl = lane & 7;
  const int beg = offs[wid], n = deg[wid];
  float acc[8];
  #pragma unroll
  for(int e=0;e<8;e++) acc[e]=0.f;
  int i = 0;
  for(; i+64 <= n; i += 64){
    int s[8];
    #pragma unroll
    for(int j=0;j<8;j++) s[j] = csr[beg + i + 8*j + sub];
    #pragma unroll
    for(int j=0;j<8;j++){
      bf16x8 u = *(const bf16x8*)(xH + (size_t)s[j]*64 + fl*8);
      #pragma unroll
      for(int e=0;e<8;e++) acc[e] += bf2f((unsigned short)u[e]);
    }
  }
  for(; i < n; i += 8){
    if(i + sub < n){
      int s = csr[beg + i + sub];
      bf16x8 u = *(const bf16x8*)(xH + (size_t)s*64 + fl*8);
      #pragma unroll
      for(int e=0;e<8;e++) acc[e] += bf2f((unsigned short)u[e]);
    }
  }
  #pragma unroll
  for(int e=0;e<8;e++){
    acc[e] += __shfl_xor(acc[e], 8);
    acc[e] += __shfl_xor(acc[e], 16);
    acc[e] += __shfl_xor(acc[e], 32);
  }
  if(sub == 0){
    ushort4 h0,h1,l0,l1;
    h0.x=f2bf(acc[0]); l0.x=f2bf(acc[0]-bf2f(h0.x));
    h0.y=f2bf(acc[1]); l0.y=f2bf(acc[1]-bf2f(h0.y));
    h0.z=f2bf(acc[2]); l0.z=f2bf(acc[2]-bf2f(h0.z));
    h0.w=f2bf(acc[3]); l0.w=f2bf(acc[3]-bf2f(h0.w));
    h1.x=f2bf(acc[4]); l1.x=f2bf(acc[4]-bf2f(h1.x));
    h1.y=f2bf(acc[5]); l1.y=f2bf(acc[5]-bf2f(h1.y));
    h1.z=f2bf(acc[6]); l1.z=f2bf(acc[6]-bf2f(h1.z));
    h1.w=f2bf(acc[7]); l1.w=f2bf(acc[7]-bf2f(h1.w));
    *(ushort4*)(aH + (size_t)wid*64 + fl*8)     = h0;
    *(ushort4*)(aH + (size_t)wid*64 + fl*8 + 4) = h1;
    *(ushort4*)(aL + (size_t)wid*64 + fl*8)     = l0;
    *(ushort4*)(aL + (size_t)wid*64 + fl*8 + 4) = l1;
  }
}

__global__ __launch_bounds__(256) void k_aggr128(const unsigned short* __restrict__ qH,
                                                 const int* __restrict__ offs, const int* __restrict__ deg,
                                                 const unsigned short* __restrict__ csr,
                                                 unsigned short* __restrict__ aH,
                                                 unsigned short* __restrict__ aL){
  const int wid  = (blockIdx.x*256 + threadIdx.x) >> 6;
  const int lane = threadIdx.x & 63;
  const int sub = lane >> 4, fl = lane & 15;
  const int beg = offs[wid], n = deg[wid];
  float acc[8];
  #pragma unroll
  for(int e=0;e<8;e++) acc[e]=0.f;
  int i = 0;
  for(; i+32 <= n; i += 32){
    int s[8];
    #pragma unroll
    for(int j=0;j<8;j++) s[j] = csr[beg + i + 4*j + sub];
    #pragma unroll
    for(int j=0;j<8;j++){
      bf16x8 u = *(const bf16x8*)(qH + (size_t)s[j]*128 + fl*8);
      #pragma unroll
      for(int e=0;e<8;e++) acc[e] += bf2f((unsigned short)u[e]);
    }
  }
  for(; i < n; i += 4){
    if(i + sub < n){
      int s = csr[beg + i + sub];
      bf16x8 u = *(const bf16x8*)(qH + (size_t)s*128 + fl*8);
      #pragma unroll
      for(int e=0;e<8;e++) acc[e] += bf2f((unsigned short)u[e]);
    }
  }
  #pragma unroll
  for(int e=0;e<8;e++){
    acc[e] += __shfl_xor(acc[e], 16);
    acc[e] += __shfl_xor(acc[e], 32);
  }
  if(sub == 0){
    ushort4 h0,h1,l0,l1;
    h0.x=f2bf(acc[0]); l0.x=f2bf(acc[0]-bf2f(h0.x));
    h0.y=f2bf(acc[1]); l0.y=f2bf(acc[1]-bf2f(h0.y));
    h0.z=f2bf(acc[2]); l0.z=f2bf(acc[2]-bf2f(h0.z));
    h0.w=f2bf(acc[3]); l0.w=f2bf(acc[3]-bf2f(h0.w));
    h1.x=f2bf(acc[4]); l1.x=f2bf(acc[4]-bf2f(h1.x));
    h1.y=f2bf(acc[5]); l1.y=f2bf(acc[5]-bf2f(h1.y));
    h1.z=f2bf(acc[6]); l1.z=f2bf(acc[6]-bf2f(h1.z));
    h1.w=f2bf(acc[7]); l1.w=f2bf(acc[7]-bf2f(h1.w));
    *(ushort4*)(aH + (size_t)wid*128 + fl*8)     = h0;
    *(ushort4*)(aH + (size_t)wid*128 + fl*8 + 4) = h1;
    *(ushort4*)(aL + (size_t)wid*128 + fl*8)     = l0;
    *(ushort4*)(aL + (size_t)wid*128 + fl*8 + 4) = l1;
  }
}

// ---------------- lin via split-bf16 MFMA, B-resident, 64 rows/block ------------
// 4 independent MFMA chains (ks even/odd x 2 cols). Barrier only when out aliases X.
template<int KD, bool ALIAS, bool STATS>
__global__ __launch_bounds__(256) void k_ling(const unsigned short* __restrict__ AH,
                                              const unsigned short* __restrict__ AL,
                                              const unsigned short* XH,
                                              const unsigned short* XL,
                                              const unsigned short* __restrict__ WT,
                                              const float* __restrict__ W, int bofs,
                                              unsigned short* outH,
                                              unsigned short* outL,
                                              float* bnsum, float* bnsq){
  constexpr int NK = KD/32;
  const int t = threadIdx.x;
  const int wv = t>>6, lane = t&63, quad = lane>>4, m = lane&15;
  const int rbase = blockIdx.x*64;
  const int c0 = (wv*2)*16 + m;
  const int c1 = (wv*2+1)*16 + m;

  bf16x8 BrH0[NK], BrL0[NK], BoH0[NK], BoL0[NK];
  bf16x8 BrH1[NK], BrL1[NK], BoH1[NK], BoL1[NK];
  #pragma unroll
  for(int ks=0; ks<NK; ks++){
    const size_t o0 = (size_t)c0*KD + ks*32 + quad*8;
    const size_t o1 = (size_t)c1*KD + ks*32 + quad*8;
    BrH0[ks] = *(const bf16x8*)(WT + o0);
    BrL0[ks] = *(const bf16x8*)(WT + 128*KD + o0);
    BoH0[ks] = *(const bf16x8*)(WT + 256*KD + o0);
    BoL0[ks] = *(const bf16x8*)(WT + 384*KD + o0);
    BrH1[ks] = *(const bf16x8*)(WT + o1);
    BrL1[ks] = *(const bf16x8*)(WT + 128*KD + o1);
    BoH1[ks] = *(const bf16x8*)(WT + 256*KD + o1);
    BoL1[ks] = *(const bf16x8*)(WT + 384*KD + o1);
  }
  const float b0 = W[bofs + c0];
  const float b1 = W[bofs + c1];
  float s1a=0.f, s2a=0.f, s1b=0.f, s2b=0.f;

  for(int rt=0; rt<4; rt++){
    const int r0 = rbase + rt*16;
    bf16x8 fah[NK], fal[NK], fxh[NK], fxl[NK];
    #pragma unroll
    for(int ks=0; ks<NK; ks++){
      const size_t o = (size_t)(r0+m)*KD + ks*32 + quad*8;
      fah[ks] = *(const bf16x8*)(AH + o);
      fal[ks] = *(const bf16x8*)(AL + o);
      fxh[ks] = *(const bf16x8*)(XH + o);
      fxl[ks] = *(const bf16x8*)(XL + o);
    }
    // 4 independent accumulator chains: (col0,col1) x (ks even, ks odd)
    f32x4 a0e={0.f,0.f,0.f,0.f}, a0o={0.f,0.f,0.f,0.f};
    f32x4 a1e={0.f,0.f,0.f,0.f}, a1o={0.f,0.f,0.f,0.f};
    #pragma unroll
    for(int kp=0; kp<NK; kp+=2){
      a0e = __builtin_amdgcn_mfma_f32_16x16x32_bf16(fah[kp], BrH0[kp], a0e, 0,0,0);
      a1e = __builtin_amdgcn_mfma_f32_16x16x32_bf16(fah[kp], BrH1[kp], a1e, 0,0,0);
      a0o = __builtin_amdgcn_mfma_f32_16x16x32_bf16(fah[kp+1], BrH0[kp+1], a0o, 0,0,0);
      a1o = __builtin_amdgcn_mfma_f32_16x16x32_bf16(fah[kp+1], BrH1[kp+1], a1o, 0,0,0);
      a0e = __builtin_amdgcn_mfma_f32_16x16x32_bf16(fal[kp], BrH0[kp], a0e, 0,0,0);
      a1e = __builtin_amdgcn_mfma_f32_16x16x32_bf16(fal[kp], BrH1[kp], a1e, 0,0,0);
      a0o = __builtin_amdgcn_mfma_f32_16x16x32_bf16(fal[kp+1], BrH0[kp+1], a0o, 0,0,0);
      a1o = __builtin_amdgcn_mfma_f32_16x16x32_bf16(fal[kp+1], BrH1[kp+1], a1o, 0,0,0);
      a0e = __builtin_amdgcn_mfma_f32_16x16x32_bf16(fah[kp], BrL0[kp], a0e, 0,0,0);
      a1e = __builtin_amdgcn_mfma_f32_16x16x32_bf16(fah[kp], BrL1[kp], a1e, 0,0,0);
      a0o = __builtin_amdgcn_mfma_f32_16x16x32_bf16(fah[kp+1], BrL0[kp+1], a0o, 0,0,0);
      a1o = __builtin_amdgcn_mfma_f32_16x16x32_bf16(fah[kp+1], BrL1[kp+1], a1o, 0,0,0);
      a0e = __builtin_amdgcn_mfma_f32_16x16x32_bf16(fxh[kp], BoH0[kp], a0e, 0,0,0);
      a1e = __builtin_amdgcn_mfma_f32_16x16x32_bf16(fxh[kp], BoH1[kp], a1e, 0,0,0);
      a0o = __builtin_amdgcn_mfma_f32_16x16x32_bf16(fxh[kp+1], BoH0[kp+1], a0o, 0,0,0);
      a1o = __builtin_amdgcn_mfma_f32_16x16x32_bf16(fxh[kp+1], BoH1[kp+1], a1o, 0,0,0);
      a0e = __builtin_amdgcn_mfma_f32_16x16x32_bf16(fxl[kp], BoH0[kp], a0e, 0,0,0);
      a1e = __builtin_amdgcn_mfma_f32_16x16x32_bf16(fxl[kp], BoH1[kp], a1e, 0,0,0);
      a0o = __builtin_amdgcn_mfma_f32_16x16x32_bf16(fxl[kp+1], BoH0[kp+1], a0o, 0,0,0);
      a1o = __builtin_amdgcn_mfma_f32_16x16x32_bf16(fxl[kp+1], BoH1[kp+1], a1o, 0,0,0);
      a0e = __builtin_amdgcn_mfma_f32_16x16x32_bf16(fxh[kp], BoL0[kp], a0e, 0,0,0);
      a1e = __builtin_amdgcn_mfma_f32_16x16x32_bf16(fxh[kp], BoL1[kp], a1e, 0,0,0);
      a0o = __builtin_amdgcn_mfma_f32_16x16x32_bf16(fxh[kp+1], BoL0[kp+1], a0o, 0,0,0);
      a1o = __builtin_amdgcn_mfma_f32_16x16x32_bf16(fxh[kp+1], BoL1[kp+1], a1o, 0,0,0);
    }
    if(ALIAS) __syncthreads();   // block-wide reads of tile rt done before its writes
    #pragma unroll
    for(int i=0;i<4;i++){
      const size_t orow = (size_t)(r0 + quad*4 + i)*128;
      float v0 = fmaxf(a0e[i] + a0o[i] + b0, 0.f);
      unsigned short h0 = f2bf(v0);
      outH[orow + c0] = h0;
      outL[orow + c0] = f2bf(v0 - bf2f(h0));
      float v1 = fmaxf(a1e[i] + a1o[i] + b1, 0.f);
      unsigned short h1 = f2bf(v1);
      outH[orow + c1] = h1;
      outL[orow + c1] = f2bf(v1 - bf2f(h1));
      if(STATS){
        s1a += v0; s2a += v0*v0;
        s1b += v1; s2b += v1*v1;
      }
    }
  }
  if(STATS){
    s1a += __shfl_xor(s1a,16); s1a += __shfl_xor(s1a,32);
    s2a += __shfl_xor(s2a,16); s2a += __shfl_xor(s2a,32);
    s1b += __shfl_xor(s1b,16); s1b += __shfl_xor(s1b,32);
    s2b += __shfl_xor(s2b,16); s2b += __shfl_xor(s2b,32);
    if(quad == 0){
      atomicAdd(&bnsum[c0], s1a); atomicAdd(&bnsq[c0], s2a);
      atomicAdd(&bnsum[c1], s1b); atomicAdd(&bnsq[c1], s2b);
    }
  }
}

__global__ __launch_bounds__(256) void k_bnfin(const float* __restrict__ bnsum, const float* __restrict__ bnsq,
                                               const float* __restrict__ W,
                                               float* scale, float* shift, float* ksq0, float* ksq1){
  const int t = threadIdx.x;
  if(t < 128){
    double mu  = (double)bnsum[t] / (double)NTOT;
    double var = (double)bnsq[t] / (double)NTOT - mu*mu;
    if(var < 0.0) var = 0.0;
    float sc = W[W_GAMMA + t] * rsqrtf((float)var + 1e-5f);
    scale[t] = sc;
    shift[t] = W[W_BETA + t] - (float)mu * sc;
  }
  if(t < HEADS*K1){
    float s=0.f;
    for(int f=0;f<128;f++){ float v = W[W_KEYS0 + t*128 + f]; s += v*v; }
    ksq0[t] = s;
  }
  if(t < HEADS*K2){
    float s=0.f;
    for(int f=0;f<100;f++){ float v = W[W_KEYS1 + t*100 + f]; s += v*v; }
    ksq1[t] = s;
  }
}

// ---------------- memconv0 stage A: fused qk MFMA + C + partial cn ------------
__global__ __launch_bounds__(256) void k_memA(
    const unsigned short* __restrict__ qH, const unsigned short* __restrict__ qL,
    const float* __restrict__ scale, const float* __restrict__ shift,
    const unsigned short* __restrict__ k0b,
    const float* __restrict__ W, const float* __restrict__ ksq,
    float* __restrict__ Cg, float* __restrict__ cn)
{
  __shared__ unsigned short Qb[64*136];
  __shared__ float qkL[160*68];        // [col][row]
  __shared__ float wsumL[64*36];
  __shared__ float qsqL[64];
  __shared__ float rsL[64*6];
  const int bid = blockIdx.x;
  const int r0 = bid*64;
  const int t = threadIdx.x;
  const int wv = t>>6, lane = t&63, quad = lane>>4, m = lane&15;

  for(int idx=t; idx<64*32; idx+=256){
    int r = idx>>5, c4 = (idx&31)*4;
    size_t o = (size_t)(r0+r)*128 + c4;
    ushort4 uh = *(const ushort4*)(qH + o);
    ushort4 ul = *(const ushort4*)(qL + o);
    float4 s = *(const float4*)(scale + c4);
    float4 h = *(const float4*)(shift + c4);
    ushort4 ob;
    ob.x = f2bf((bf2f(uh.x)+bf2f(ul.x))*s.x + h.x);
    ob.y = f2bf((bf2f(uh.y)+bf2f(ul.y))*s.y + h.y);
    ob.z = f2bf((bf2f(uh.z)+bf2f(ul.z))*s.z + h.z);
    ob.w = f2bf((bf2f(uh.w)+bf2f(ul.w))*s.w + h.w);
    *(ushort4*)(Qb + r*136 + c4) = ob;
  }
  __syncthreads();

  {
    bf16x8 a[4];
    #pragma unroll
    for(int ks=0;ks<4;ks++)
      a[ks] = *(const bf16x8*)(Qb + (wv*16+m)*136 + ks*32 + quad*8);
    for(int nb=0; nb<10; nb++){
      f32x4 acc = {0.f,0.f,0.f,0.f};
      const bf16x8* brow = (const bf16x8*)(k0b + (size_t)(nb*16+m)*128);
      #pragma unroll
      for(int ks=0;ks<4;ks++)
        acc = __builtin_amdgcn_mfma_f32_16x16x32_bf16(a[ks], brow[ks*4+quad], acc,0,0,0);
      *(f32x4*)(qkL + (nb*16+m)*68 + wv*16 + quad*4) = acc;
    }
  }
  if(t < 64){
    float s = 0.f;
    for(int j=0;j<16;j++){
      bf16x8 v = *(const bf16x8*)(Qb + t*136 + j*8);
      #pragma unroll
      for(int e=0;e<8;e++){ float f = bf2f((unsigned short)v[e]); s += f*f; }
    }
    qsqL[t] = s;
  }
  __syncthreads();

  {
    int row = t & 63, g = t >> 6;
    float q2 = qsqL[row];
    #pragma unroll
    for(int pass=0; pass<2; pass++){
      int h = g + pass*4;
      if(h < HEADS){
        float rs = 0.f;
        for(int k=0;k<32;k++){
          float d2 = q2 + ksq[h*32+k] - 2.f*qkL[(h*32+k)*68 + row];
          d2 = fmaxf(d2, 1e-12f);
          rs += 1.f/(1.f+d2);
        }
        rsL[row*6+h] = W[W_CONVW0+h]/fmaxf(rs,1e-20f);
      }
    }
  }
  __syncthreads();

  {
    int row = t & 63, kq = t >> 6;
    float q2 = qsqL[row];
    for(int kk=0; kk<8; kk++){
      int k = kq*8+kk;
      float wsum = 0.f;
      #pragma unroll
      for(int h=0;h<HEADS;h++){
        float d2 = q2 + ksq[h*32+k] - 2.f*qkL[(h*32+k)*68 + row];
        d2 = fmaxf(d2, 1e-12f);
        wsum += rsL[row*6+h]/(1.f+d2);
      }
      wsumL[row*36+k] = wsum;
    }
  }
  __syncthreads();

  if(t < 64){
    float mx = -1e30f;
    #pragma unroll
    for(int k=0;k<32;k++) mx = fmaxf(mx, wsumL[t*36+k]);
    float cv[32]; float se = 0.f;
    #pragma unroll
    for(int k=0;k<32;k++){ float e = __expf(wsumL[t*36+k]-mx); cv[k]=e; se+=e; }
    float inv = 1.f/se;
    #pragma unroll
    for(int k=0;k<32;k++){ cv[k]*=inv; wsumL[t*36+k]=cv[k]; }
    float4* dst = (float4*)(Cg + (size_t)(r0+t)*32);
    #pragma unroll
    for(int k4=0;k4<8;k4++)
      dst[k4] = (float4){cv[k4*4],cv[k4*4+1],cv[k4*4+2],cv[k4*4+3]};
  }
  __syncthreads();
  if(t < 32){
    float s = 0.f;
    for(int r=0;r<64;r++) s += wsumL[r*36+t];
    atomicAdd(&cn[(bid>>2)*32 + t], s);
  }
}

// ---------------- memconv0 stage B: KL ----------------
__global__ __launch_bounds__(256) void k_memB(const float* __restrict__ Cg,
                                              const float* __restrict__ cn,
                                              float* __restrict__ klacc){
  __shared__ float cn_s[32];
  __shared__ float red_s[4];
  const int b = blockIdx.x, t = threadIdx.x;
  if(t < 32) cn_s[t] = cn[b*32+t] + EPSF;
  __syncthreads();
  const float* crow = Cg + ((size_t)b*256 + t)*32;
  float cv[32]; float pn = 0.f;
  #pragma unroll
  for(int k4=0;k4<8;k4++){
    float4 u = *(const float4*)(crow + k4*4);
    cv[k4*4]=u.x; cv[k4*4+1]=u.y; cv[k4*4+2]=u.z; cv[k4*4+3]=u.w;
  }
  #pragma unroll
  for(int k=0;k<32;k++) pn += cv[k]*cv[k]/cn_s[k];
  pn += EPSF;
  float acc = 0.f;
  #pragma unroll
  for(int k=0;k<32;k++){
    float P = cv[k]*cv[k]/(cn_s[k]*pn);
    acc += P*(__logf(P+EPSF) - __logf(cv[k]+EPSF));
  }
  #pragma unroll
  for(int off=32; off>0; off>>=1) acc += __shfl_down(acc, off);
  if((t&63)==0) red_s[t>>6] = acc;
  __syncthreads();
  if(t==0) atomicAdd(klacc, 100.f*(red_s[0]+red_s[1]+red_s[2]+red_s[3]));
}

// ---------------- memconv0 stage V: V = C^T Q ----------------
__global__ __launch_bounds__(256) void k_memV(const float* __restrict__ Cg,
                                              const unsigned short* __restrict__ qH,
                                              const unsigned short* __restrict__ qL,
                                              const float* __restrict__ scale,
                                              const float* __restrict__ shift,
                                              float* __restrict__ V){
  __shared__ float Cs[256*36];
  __shared__ float Qs[256*32];
  const int b  = blockIdx.x >> 2;
  const int f0 = (blockIdx.x & 3) * 32;
  const int t = threadIdx.x;
  for(int idx=t; idx<256*8; idx+=256){
    int n = idx>>3, k4 = (idx&7)*4;
    *(float4*)(Cs + n*36 + k4) = *(const float4*)(Cg + ((size_t)b*256+n)*32 + k4);
  }
  for(int idx=t; idx<256*8; idx+=256){
    int n = idx>>3, j4 = (idx&7)*4;
    size_t o = ((size_t)b*256+n)*128 + f0 + j4;
    ushort4 uh = *(const ushort4*)(qH + o);
    ushort4 ul = *(const ushort4*)(qL + o);
    float4 s = *(const float4*)(scale + f0 + j4);
    float4 h = *(const float4*)(shift + f0 + j4);
    *(float4*)(Qs + n*32 + j4) = (float4){
      (bf2f(uh.x)+bf2f(ul.x))*s.x + h.x,
      (bf2f(uh.y)+bf2f(ul.y))*s.y + h.y,
      (bf2f(uh.z)+bf2f(ul.z))*s.z + h.z,
      (bf2f(uh.w)+bf2f(ul.w))*s.w + h.w};
  }
  __syncthreads();
  const int k = t & 31, fg = t >> 5;
  float v0=0.f,v1=0.f,v2=0.f,v3=0.f;
  for(int n=0;n<256;n++){
    float c = Cs[n*36+k];
    float4 q = *(const float4*)(Qs + n*32 + fg*4);
    v0 += c*q.x; v1 += c*q.y; v2 += c*q.z; v3 += c*q.w;
  }
  *(float4*)(V + ((size_t)b*32 + k)*128 + f0 + fg*4) = (float4){v0,v1,v2,v3};
}

// ---------------- memconv0 stage L: lin0 ----------------
__global__ __launch_bounds__(256) void k_memL(const float* __restrict__ V,
                                              const float* __restrict__ W,
                                              float* __restrict__ mq1){
  __shared__ float Vs[32*132];
  const int b = blockIdx.x, t = threadIdx.x;
  for(int idx=t; idx<32*32; idx+=256){
    int k = idx>>5, j4 = (idx&31)*4;
    *(float4*)(Vs + k*132 + j4) = *(const float4*)(V + ((size_t)b*32+k)*128 + j4);
  }
  __syncthreads();
  for(int idx=t; idx<K1*MEMH; idx+=256){
    int k = idx/100, mc = idx - k*100;
    float a = W[W_LINB0 + mc];
    for(int f=0; f<128; f++) a += Vs[k*132+f]*W[W_LINW0 + f*100 + mc];
    mq1[(size_t)(b*32+k)*100 + mc] = (a>0.f) ? a : 0.01f*a;
  }
}

// ---------------- mem conv 1 ----------------
__global__ __launch_bounds__(256) void k_memconv1(
    const float* __restrict__ mq1, const float* __restrict__ W,
    const float* __restrict__ ksq, float* __restrict__ mq2, float* __restrict__ klacc)
{
  __shared__ float Qs[32*104];
  __shared__ float Ks[40*100];
  __shared__ float QKs[32*40];
  __shared__ float Cs[32*8];
  __shared__ float cn_s[8];
  __shared__ float pn_s[32];
  __shared__ float qsq_s[32];
  __shared__ float Vs[8*100];
  __shared__ float red_s[4];
  const int b = blockIdx.x, t = threadIdx.x;

  for(int idx=t; idx<32*100; idx+=256){
    int n = idx/100, f = idx - n*100;
    Qs[n*104+f] = mq1[(size_t)b*3200 + idx];
  }
  for(int idx=t; idx<40*100; idx+=256) Ks[idx] = W[W_KEYS1 + idx];
  __syncthreads();

  if(t < 32){ float s=0.f; for(int f=0;f<100;f++){ float v=Qs[t*104+f]; s+=v*v; } qsq_s[t]=s; }
  for(int idx=t; idx<32*40; idx+=256){
    int n = idx/40, c = idx - n*40;
    float a = 0.f;
    for(int f=0;f<100;f++) a += Qs[n*104+f]*Ks[c*100+f];
    QKs[idx] = a;
  }
  __syncthreads();

  if(t < 32){
    float wsum[8];
    #pragma unroll
    for(int k=0;k<8;k++) wsum[k]=0.f;
    for(int h=0;h<HEADS;h++){
      float cw = W[W_CONVW1 + h];
      float c[8]; float rs=0.f;
      #pragma unroll
      for(int k=0;k<8;k++){
        float d2 = qsq_s[t] + ksq[h*8+k] - 2.f*QKs[t*40 + h*8+k];
        d2 = fmaxf(d2, 1e-12f);
        float cc = 1.f/(1.f+d2);
        c[k]=cc; rs+=cc;
      }
      float sc = cw/fmaxf(rs, 1e-20f);
      #pragma unroll
      for(int k=0;k<8;k++) wsum[k] += c[k]*sc;
    }
    float mx = wsum[0];
    #pragma unroll
    for(int k=1;k<8;k++) mx = fmaxf(mx, wsum[k]);
    float se=0.f;
    #pragma unroll
    for(int k=0;k<8;k++){ float e=__expf(wsum[k]-mx); wsum[k]=e; se+=e; }
    float inv = 1.f/se;
    #pragma unroll
    for(int k=0;k<8;k++) Cs[t*8+k] = wsum[k]*inv;
  }
  __syncthreads();
  if(t < 8){ float s=0.f; for(int n=0;n<32;n++) s += Cs[n*8+t]; cn_s[t]=s+EPSF; }
  __syncthreads();
  if(t < 32){
    float p=0.f;
    #pragma unroll
    for(int k=0;k<8;k++){ float sv=Cs[t*8+k]; p += sv*sv/cn_s[k]; }
    pn_s[t]=p+EPSF;
  }
  __syncthreads();

  float acc;
  {
    int n = t>>3, k = t&7;
    float sv = Cs[t];
    float P = sv*sv/(cn_s[k]*pn_s[n]);
    acc = P*(__logf(P+EPSF) - __logf(sv+EPSF));
  }
  #pragma unroll
  for(int off=32; off>0; off>>=1) acc += __shfl_down(acc, off);
  if((t&63)==0) red_s[t>>6] = acc;

  for(int idx=t; idx<8*100; idx+=256){
    int k = idx/100, f = idx - k*100;
    float a=0.f;
    for(int n=0;n<32;n++) a += Cs[n*8+k]*Qs[n*104+f];
    Vs[idx] = a;
  }
  __syncthreads();

  if(t==0) atomicAdd(klacc, 100.f*(red_s[0]+red_s[1]+red_s[2]+red_s[3]));

  for(int idx=t; idx<8*100; idx+=256){
    int k = idx/100, mc = idx - k*100;
    float a = W[W_LINB1 + mc];
    for(int f=0;f<100;f++) a += Vs[k*100+f]*W[W_LINW1 + f*100 + mc];
    mq2[(size_t)b*800 + idx] = (a>0.f) ? a : 0.01f*a;
  }
}

// ---------------- head ----------------
__global__ __launch_bounds__(128) void k_final(const float* __restrict__ mq2,
                                               const float* __restrict__ W,
                                               const int* __restrict__ flag,
                                               const float* __restrict__ kl,
                                               void* __restrict__ out){
  __shared__ float h_s[100];
  __shared__ float hid_s[50];
  const int b = blockIdx.x, t = threadIdx.x;
  if(t < 100){
    float s=0.f;
    #pragma unroll
    for(int k=0;k<8;k++) s += mq2[(size_t)b*800 + k*100 + t];
    h_s[t] = s*0.125f;
  }
  __syncthreads();
  if(t < 50){
    float a = W[W_MLPB1 + t];
    for(int f=0;f<100;f++) a += h_s[f]*W[W_MLPW1 + f*50 + t];
    hid_s[t] = (a>0.f) ? a : 0.01f*a;
  }
  __syncthreads();
  if(t < 12){
    float a = W[W_MLPB2 + t];
    #pragma unroll
    for(int j=0;j<50;j++) a += hid_s[j]*W[W_MLPW2 + j*12 + t];
    if(flag[0]) ((__hip_bfloat16*)out)[b*12+t] = __float2bfloat16(a);
    else        ((float*)out)[b*12+t] = a;
  }
  if(b==0 && t==64){
    float v = (kl[0]+kl[1]) * (1.f/65536.f);
    if(flag[0]) ((__hip_bfloat16*)out)[3072] = __float2bfloat16(v);
    else        ((float*)out)[3072] = v;
  }
}

// ---------------- launch ----------------
extern "C" void kernel_launch(void* const* d_in, const int* in_sizes, int n_in,
                              void* d_out, int out_size, void* d_ws, size_t ws_size,
                              hipStream_t stream) {
  (void)in_sizes; (void)n_in; (void)out_size; (void)ws_size;
  const void* x   = d_in[0];
  const int*  ei  = (const int*)d_in[1];
  const int* src = ei;
  const int* dst = ei + NEDGE;

  WPtrs wp;
  for(int i=0;i<20;i++) wp.p[i] = d_in[3+i];

  char* w = (char*)d_ws;
  int*    deg    = (int*)   (w + OFF_DEG);
  int*    bh2    = (int*)   (w + OFF_BH2);
  int*    offs   = (int*)   (w + OFF_OFFS);
  float*  bnsum  = (float*) (w + OFF_BNSUM);
  float*  bnsq   = (float*) (w + OFF_BNSQ);
  float*  scale  = (float*) (w + OFF_SCALE);
  float*  shift  = (float*) (w + OFF_SHIFT);
  float*  ksq0   = (float*) (w + OFF_KSQ0);
  float*  ksq1   = (float*) (w + OFF_KSQ1);
  float*  kl     = (float*) (w + OFF_KL);
  int*    flag   = (int*)   (w + OFF_FLAG);
  float*  Wc     = (float*) (w + OFF_W);
  unsigned short* k0b = (unsigned short*)(w + OFF_K0B);
  unsigned short* wt1 = (unsigned short*)(w + OFF_WT1);
  unsigned short* wt2 = (unsigned short*)(w + OFF_WT2);
  float*  cn     = (float*) (w + OFF_CN);
  int*    ebase  = (int*)   (w + OFF_EBASE);
  int*    bcur   = (int*)   (w + OFF_BCUR);
  unsigned short* csr = (unsigned short*)(w + OFF_CSR);
  unsigned int*   ebuf = (unsigned int*)(w + OFF_EBUF);
  unsigned short* agH64  = (unsigned short*)(w + OFF_AH64);
  unsigned short* agL64  = (unsigned short*)(w + OFF_AL64);
  unsigned short* agH128 = (unsigned short*)(w + OFF_AH128);
  unsigned short* agL128 = (unsigned short*)(w + OFF_AL128);
  unsigned short* qvH    = (unsigned short*)(w + OFF_QH);
  unsigned short* qvL    = (unsigned short*)(w + OFF_QL);
  unsigned short* xcH    = (unsigned short*)(w + OFF_XH);
  unsigned short* xcL    = (unsigned short*)(w + OFF_XL);
  float*  Cg     = (float*) (w + OFF_CG);
  float*  Vbuf   = (float*) (w + OFF_V);
  float*  mq1    = (float*) (w + OFF_MQ1);
  float*  mq2    = (float*) (w + OFF_MQ2);

  unsigned short* qbnH = qvH;
  unsigned short* qbnL = qvL;

  k_pre    <<<256,   256, 0, stream>>>((const unsigned short*)x, dst, flag, bnsum, bnsq, kl, cn, bh2);
  k_bscan  <<<1,     256, 0, stream>>>(bh2, ebase, bcur);
  k_bin2   <<<256,   256, 0, stream>>>(src, dst, bcur, ebuf);
  k_fine   <<<256,   256, 0, stream>>>(ebuf, ebase, csr, deg, offs);
  k_cvtx   <<<16384, 256, 0, stream>>>(x, flag, xcH, xcL);
  k_cvtw   <<<482,   256, 0, stream>>>(wp, flag, Wc, k0b, wt1, wt2);
  k_aggr64 <<<16384, 256, 0, stream>>>(xcH, offs, deg, csr, agH64, agL64);
  k_ling<64,false,false> <<<1024, 256, 0, stream>>>(agH64, agL64, xcH, xcL, wt1, Wc, W_BREL0, qvH, qvL, bnsum, bnsq);
  k_aggr128<<<16384, 256, 0, stream>>>(qvH, offs, deg, csr, agH128, agL128);
  k_ling<128,true,true><<<1024, 256, 0, stream>>>(agH128, agL128, qvH, qvL, wt2, Wc, W_BREL1, qbnH, qbnL, bnsum, bnsq);
  k_bnfin  <<<1,     256, 0, stream>>>(bnsum, bnsq, Wc, scale, shift, ksq0, ksq1);
  k_memA   <<<1024,  256, 0, stream>>>(qbnH, qbnL, scale, shift, k0b, Wc, ksq0, Cg, cn);
  k_memB   <<<256,   256, 0, stream>>>(Cg, cn, kl);
  k_memV   <<<1024,  256, 0, stream>>>(Cg, qbnH, qbnL, scale, shift, Vbuf);
  k_memL   <<<256,   256, 0, stream>>>(Vbuf, Wc, mq1);
  k_memconv1<<<256,  256, 0, stream>>>(mq1, Wc, ksq1, mq2, kl+1);
  k_final  <<<256,   128, 0, stream>>>(mq2, Wc, flag, kl, d_out);
}